// Round 3
// baseline (316.613 us; speedup 1.0000x reference)
//
#include <hip/hip_runtime.h>
#include <math.h>

#ifndef M_PI
#define M_PI 3.14159265358979323846
#endif

#define N_FFT       512
#define N_BINS      257
#define N_FILTERS   128
#define OUTPUT_SIZE 262144
#define N_TIMESTEPS 128

// ---- ordered-uint64 encoding for deterministic double atomic min/max ----
__device__ __forceinline__ unsigned long long enc_d(double f) {
    unsigned long long u = (unsigned long long)__double_as_longlong(f);
    return (u & 0x8000000000000000ull) ? ~u : (u | 0x8000000000000000ull);
}
__device__ __forceinline__ double dec_d(unsigned long long e) {
    unsigned long long u = (e & 0x8000000000000000ull) ? (e ^ 0x8000000000000000ull) : ~e;
    return __longlong_as_double((long long)u);
}

// ============================================================================
// K1: front-end (single block, 256 threads) — FULL FP64 pipeline.
//   - 512-pt real DFT in fp64 (matches numpy float64 rfft to ~1e-13)
//   - magnitude: fp64 -> fp32 cast (the reference's explicit .astype(float32)),
//     then promoted back to fp64 for everything downstream
//   - cochlear = fb @ mag            (fp64, NO fp32 rounding)
//   - hair = pow(cochlear + 1e-6, 0.3)   (double exponent 0.3)
//   - adapted = relu(hair - adapt*0.5)   (fp64)  -> ws (double)
//   - init min/max atomic slots (u64)
// ============================================================================
__global__ __launch_bounds__(256) void k1_frontend(
    const float* __restrict__ audio, const float* __restrict__ fb,
    const float* __restrict__ adapt, double* __restrict__ adapted,
    unsigned long long* __restrict__ minmax)
{
    __shared__ double tw_c[N_FFT];
    __shared__ double tw_s[N_FFT];
    __shared__ double aud[N_FFT];
    __shared__ float  mag[N_BINS];

    const int tid = threadIdx.x;

    for (int m = tid; m < N_FFT; m += 256) {
        double ang = (-2.0 * M_PI * (double)m) / (double)N_FFT;
        double s, c;
        sincos(ang, &s, &c);
        tw_c[m] = c;
        tw_s[m] = s;
        aud[m] = (double)audio[m];   // rfft(n=512) truncates to first 512 samples
    }
    __syncthreads();

    for (int b = tid; b < N_BINS; b += 256) {
        double re = 0.0, im = 0.0;
        int m = 0;
        for (int n = 0; n < N_FFT; ++n) {
            double a = aud[n];
            re += a * tw_c[m];
            im += a * tw_s[m];
            m = (m + b) & (N_FFT - 1);   // (b*n) mod 512, exact
        }
        // the reference's magnitude.astype(float32)
        mag[b] = (float)sqrt(re * re + im * im);
    }
    __syncthreads();

    if (tid < N_FILTERS) {
        double acc = 0.0;
        const float* row = fb + tid * N_BINS;
        for (int j = 0; j < N_BINS; ++j)
            acc += (double)row[j] * (double)mag[j];
        double x = acc + 1e-6;                 // + LATENCY_EPSILON (double)
        double p = pow(x, 0.3);                // double exponent
        double a = p - (double)adapt[tid] * 0.5;
        adapted[tid] = a > 0.0 ? a : 0.0;      // relu
    }
    if (tid == 0) {
        minmax[0] = 0xFFFFFFFFFFFFFFFFull;  // min slot (any enc < this)
        minmax[1] = 0ull;                   // max slot (any enc > this)
    }
}

// ============================================================================
// K2: activity = W @ adapted + b — all fp64.
//     One thread per row; float4 W loads (row = 512 B contiguous), promoted
//     to double, sequential fp64 FMA accumulate (~1e-15 rel vs numpy dgemv).
//     Block min/max reduction -> ordered-u64 atomics (deterministic).
// ============================================================================
__global__ __launch_bounds__(256) void k2_gemv(
    const float4* __restrict__ W4, const float* __restrict__ bias,
    const double* __restrict__ adapted, double* __restrict__ activity,
    unsigned long long* __restrict__ minmax)
{
    __shared__ double ad[N_FILTERS];
    __shared__ double red_min[256];
    __shared__ double red_max[256];

    const int tid = threadIdx.x;
    if (tid < N_FILTERS) ad[tid] = adapted[tid];
    __syncthreads();

    const int row = blockIdx.x * 256 + tid;
    const float4* wrow = W4 + (size_t)row * (N_FILTERS / 4);

    double acc = 0.0;
    #pragma unroll 8
    for (int j = 0; j < N_FILTERS / 4; ++j) {
        float4 w = wrow[j];
        const int k = j * 4;
        acc += (double)w.x * ad[k];
        acc += (double)w.y * ad[k + 1];
        acc += (double)w.z * ad[k + 2];
        acc += (double)w.w * ad[k + 3];
    }
    double a = acc + (double)bias[row];
    activity[row] = a;

    red_min[tid] = a;
    red_max[tid] = a;
    __syncthreads();
    for (int s = 128; s > 0; s >>= 1) {
        if (tid < s) {
            red_min[tid] = fmin(red_min[tid], red_min[tid + s]);
            red_max[tid] = fmax(red_max[tid], red_max[tid + s]);
        }
        __syncthreads();
    }
    if (tid == 0) {
        atomicMin(&minmax[0], enc_d(red_min[0]));
        atomicMax(&minmax[1], enc_d(red_max[0]));
    }
}

// ============================================================================
// K3: latency coding + full spike-matrix write.  OUTPUT IS INT32 (bool ref).
//     All fp64:
//       denom = (amax - amin) + 1e-6
//       norm  = (a - amin) / denom
//       lat   = (int)((1.0 - norm) * 127.0)     [trunc toward zero]
//       fire  = norm > 0.05
//     spikes[t][n] = (lat==t && fire) ? 1 : 0 ; every element written.
//     4 columns/thread, int4 stores, coalesced per-t (1 KB/wave/store).
// ============================================================================
__global__ __launch_bounds__(256) void k3_spikes(
    const double* __restrict__ activity,
    const unsigned long long* __restrict__ minmax,
    int4* __restrict__ out4)
{
    const int tid = blockIdx.x * 256 + threadIdx.x;  // 0..65535
    const double amin = dec_d(minmax[0]);
    const double amax = dec_d(minmax[1]);
    const double denom = (amax - amin) + 1e-6;

    const double ax = activity[4 * tid + 0];
    const double ay = activity[4 * tid + 1];
    const double az = activity[4 * tid + 2];
    const double aw = activity[4 * tid + 3];

    const double nx = (ax - amin) / denom;
    const double ny = (ay - amin) / denom;
    const double nz = (az - amin) / denom;
    const double nw = (aw - amin) / denom;

    const int lx = (int)((1.0 - nx) * 127.0);
    const int ly = (int)((1.0 - ny) * 127.0);
    const int lz = (int)((1.0 - nz) * 127.0);
    const int lw = (int)((1.0 - nw) * 127.0);

    const int vx = (nx > 0.05) ? 1 : 0;
    const int vy = (ny > 0.05) ? 1 : 0;
    const int vz = (nz > 0.05) ? 1 : 0;
    const int vw = (nw > 0.05) ? 1 : 0;

    #pragma unroll 4
    for (int t = 0; t < N_TIMESTEPS; ++t) {
        int4 v;
        v.x = (lx == t) ? vx : 0;
        v.y = (ly == t) ? vy : 0;
        v.z = (lz == t) ? vz : 0;
        v.w = (lw == t) ? vw : 0;
        out4[(size_t)t * (OUTPUT_SIZE / 4) + tid] = v;
    }
}

// ============================================================================
extern "C" void kernel_launch(void* const* d_in, const int* in_sizes, int n_in,
                              void* d_out, int out_size, void* d_ws, size_t ws_size,
                              hipStream_t stream) {
    (void)in_sizes; (void)n_in; (void)out_size; (void)ws_size;

    const float* audio = (const float*)d_in[0];   // [16000]
    const float* fb    = (const float*)d_in[1];   // [128, 257]
    const float* W     = (const float*)d_in[2];   // [262144, 128]
    const float* bias  = (const float*)d_in[3];   // [262144]
    const float* adapt = (const float*)d_in[4];   // [128]
    int* out = (int*)d_out;                       // [128, 262144] bool -> int32

    // workspace layout (poisoned 0xAA before every launch; fully re-init here)
    double* activity = (double*)d_ws;                              // 262144 f64 (2 MB)
    double* adapted  = activity + OUTPUT_SIZE;                     // 128 f64
    unsigned long long* minmax =
        (unsigned long long*)(adapted + N_FILTERS);                // 2 u64

    k1_frontend<<<1, 256, 0, stream>>>(audio, fb, adapt, adapted, minmax);
    k2_gemv<<<OUTPUT_SIZE / 256, 256, 0, stream>>>(
        (const float4*)W, bias, adapted, activity, minmax);
    k3_spikes<<<(OUTPUT_SIZE / 4) / 256, 256, 0, stream>>>(
        activity, minmax, (int4*)out);
}